// Round 5
// baseline (261.586 us; speedup 1.0000x reference)
//
#include <hip/hip_runtime.h>
#include <math.h>

#define PI_D 3.14159265358979323846

typedef short v8s __attribute__((ext_vector_type(8)));
typedef float v4f __attribute__((ext_vector_type(4)));

// ---------------- workspace layout (float offsets), total 23.6M floats = 94.4 MB ----------------
constexpr size_t OFF_PA   = 0;                   // legfwd A-frags bf16: per m, A[l][t]  (256 slices, 32 MB)
constexpr size_t OFF_PT   = 8388608;             // leginv A-frags bf16: per m, A[t][l]  (128 slices, 16 MB)
constexpr size_t OFF_SFRE = 12582912;            // flm re [m][l][c] fp32 (8 MB)
constexpr size_t OFF_SFIM = 14680064;            // flm im
constexpr size_t OFF_BF   = 16777216;            // fwd-DFT B-frags bf16 [t][ks16][nt2][lane][8] (8 MB)
constexpr size_t OFF_BF2  = 18874368;            // legfwd B-frags bf16 [m][ks8][nt4][lane][8] (8 MB)
constexpr size_t OFF_BI   = 20971520;            // inv-DFT B-frags bf16 [t][ks16][nt2][lane][8] (8 MB)
constexpr size_t OFF_AF   = 23068672;            // fwd DFT A-frags bf16 (512 KB)
constexpr size_t OFF_AI   = 23199744;            // inv DFT A-frags bf16 (512 KB)
constexpr size_t OFF_WPR  = 23330816;            // premult conv w [l][o][i] fp32
constexpr size_t OFF_WPI  = 23461888;
constexpr size_t OFF_WQ   = 23592960;            // 256 quadrature weights
constexpr size_t OFF_TC   = 23593216;            // 256 (t_cplx re|im)
constexpr size_t OFF_WLW  = 23593472;            // 128*4 l-resize weights
constexpr size_t OFF_WLI  = 23593984;            // 128*4 l-resize indices (int)
constexpr size_t OFF_WMW  = 23594496;            // 255*6 m-resize weights
constexpr size_t OFF_WMI  = 23596032;            // 255*6 m-resize indices (int)
// overlays (lifetimes disjoint):
constexpr size_t OFF_BI2  = OFF_BF;              // leginv B-frags bf16 [j][ks4][nt4][lane][8]; ONLY ks 0..3
                                                 // valid (l<128) — ks 4..7 hold stale BF data, never read!
constexpr size_t OFF_RRE  = OFF_BF2;             // resized flm [j'][l'][c] fp32 (BF2 dead after legfwd)
constexpr size_t OFF_RIM  = OFF_BF2 + 1044480;

__device__ __forceinline__ float4 ld4(const float* p) { return *(const float4*)p; }

__device__ __forceinline__ short f2bf(float f) {   // RTNE float->bf16 bits
  unsigned u = __float_as_uint(f);
  unsigned r = (u + 0x7FFFu + ((u >> 16) & 1u)) >> 16;
  return (short)r;
}

// ---------------- setup: quadrature, t_cplx, resize taps ----------------
__global__ void k_setup_small(const float* t_emb, const float* w_tr, const float* b_tr,
                              const float* w_ti, const float* b_ti, float* ws) {
  int tid = threadIdx.x;
  if (tid < 256) {
    double theta = PI_D * (2.0 * tid + 1.0) / 511.0;
    double dang = 2.0 * PI_D / 511.0;
    ws[OFF_WQ + tid] = (float)(sin(theta) * dang * dang);
  }
  if (tid < 128) {
    float sr = b_tr[tid], si = b_ti[tid];
    for (int T = 0; T < 256; ++T) {
      float e = t_emb[T];
      sr += e * w_tr[T * 128 + tid];
      si += e * w_ti[T * 128 + tid];
    }
    ws[OFF_TC + tid] = sr;
    ws[OFF_TC + 128 + tid] = si;
    double sf = 2.0 * tid + 0.5;
    double wv[4]; int iv[4]; double wsum = 0.0;
    for (int a = 0; a < 4; ++a) {
      int t = 2 * tid - 1 + a;
      double r = 1.0 - fabs(sf - (double)t) * 0.5;
      bool valid = (t >= 0 && t < 256 && r > 0.0);
      wv[a] = valid ? r : 0.0; iv[a] = valid ? t : 0;
      wsum += wv[a];
    }
    for (int a = 0; a < 4; ++a) {
      ws[OFF_WLW + tid * 4 + a] = (float)(wv[a] / wsum);
      ((int*)(ws + OFF_WLI))[tid * 4 + a] = iv[a];
    }
  }
  if (tid < 255) {
    double inv = 511.0 / 255.0;
    double sf = (tid + 0.5) * inv - 0.5;
    int t0 = (int)floor(sf) - 2;
    double wv[6]; int iv[6]; double wsum = 0.0;
    for (int b = 0; b < 6; ++b) {
      int t = t0 + b;
      double r = 1.0 - fabs(sf - (double)t) * (255.0 / 511.0);
      bool valid = (t >= 0 && t < 511 && r > 0.0);
      wv[b] = valid ? r : 0.0; iv[b] = valid ? t : 0;
      wsum += wv[b];
    }
    for (int b = 0; b < 6; ++b) {
      ws[OFF_WMW + tid * 6 + b] = (float)(wv[b] / wsum);
      ((int*)(ws + OFF_WMI))[tid * 6 + b] = iv[b];
    }
  }
}

// ---------------- premultiplied conv weights, transposed [l][o][i] ----------------
__global__ void k_wprep(const float* wr_, const float* wi_, float* ws) { // grid 512 x 256
  int gid = blockIdx.x * 256 + threadIdx.x;
  int l = gid >> 10, rem = gid & 1023, o = rem >> 5, i = rem & 31;
  float wr = wr_[(l << 10) + i * 32 + o];
  float wi = wi_[(l << 10) + i * 32 + o];
  float tcr = ws[OFF_TC + l], tci = ws[OFF_TC + 128 + l];
  ws[OFF_WPR + gid] = tcr * wr - tci * wi;
  ws[OFF_WPI + gid] = tcr * wi + tci * wr;
}

// ---------------- Legendre basis -> bf16 MFMA A-fragment tables ----------------
// PA[m]: A[row=l][col=t]; PT[m<128]: A[row=t][col=l]. Frag elem (row,col):
//   idx = (row>>4)*4096 + (col>>5)*512 + (((col>>3)&3)*16 + (row&15))*8 + (col&7)
__global__ void k_legendre(float* ws) {   // grid 256 (m) x 256 (t)
  int m = blockIdx.x, t = threadIdx.x;
  __shared__ double A[256], B[256], S[256];
  {
    int l = t;
    if (l >= 1) S[l] = -sqrt((2.0 * l + 1.0) / (2.0 * l));
    if (l >= m + 2) {
      double ll = l, mm = m;
      double den = ll * ll - mm * mm;
      A[l] = sqrt((4.0 * ll * ll - 1.0) / den);
      B[l] = sqrt((2.0 * ll + 1.0) * (ll - 1.0 - mm) * (ll - 1.0 + mm) /
                  ((2.0 * ll - 3.0) * den));
    }
  }
  __syncthreads();
  short* PAp = (short*)(ws + OFF_PA) + (size_t)m * 65536;
  short* PTp = (short*)(ws + OFF_PT) + (size_t)m * 65536;
  bool wantPT = (m < 128);
  int tlo = ((t >> 3) & 3) * 16, tj = t & 7, tks = (t >> 5) * 512, tmt = (t >> 4) * 4096, t15 = t & 15;
  double theta = PI_D * (2.0 * t + 1.0) / 511.0;
  double ct = cos(theta), st = sin(theta);
  double p0 = sqrt(1.0 / (4.0 * PI_D));
  for (int k = 1; k <= m; ++k) p0 *= S[k] * st;
  double pm1 = 0.0, pcur = 0.0;  // rolling
  for (int l = 0; l < 256; ++l) {
    float v;
    if (l < m) v = 0.f;
    else if (l == m) { pcur = p0; v = (float)pcur; }
    else if (l == m + 1) { pm1 = pcur; pcur = sqrt(2.0 * m + 3.0) * ct * pm1; v = (float)pcur; }
    else { double p2 = A[l] * ct * pcur - B[l] * pm1; pm1 = pcur; pcur = p2; v = (float)p2; }
    short bv = f2bf(v);
    PAp[(size_t)(l >> 4) * 4096 + tks + (size_t)(tlo + (l & 15)) * 8 + tj] = bv;
    if (wantPT)
      PTp[tmt + (size_t)(l >> 5) * 512 + (size_t)(((l >> 3) & 3) * 16 + t15) * 8 + (l & 7)] = bv;
  }
}

// ---------------- DFT A-fragment tables (bf16, MFMA A-operand layout) ----------------
__global__ void k_atab_f(float* ws) { // grid 1024 x 256
  int gid = blockIdx.x * 256 + threadIdx.x;   // < 262144
  int j = gid & 7, lane = (gid >> 3) & 63, ks = (gid >> 9) & 15, mt = gid >> 13;
  int m = mt * 16 + (lane & 15);              // m' : 0..255 cos rows, 256..511 -sin rows
  int k = ks * 32 + ((lane >> 4) << 3) + j;   // phi
  float v = 0.f;
  if (k < 511) {
    int mm = (m < 256) ? m : m - 256;
    int kk = (mm * k) % 511;
    double ang = (2.0 * PI_D / 511.0) * (double)kk;
    v = (m < 256) ? (float)cos(ang) : -(float)sin(ang);
  }
  ((short*)(ws + OFF_AF))[gid] = f2bf(v);
}

__global__ void k_atab_i(float* ws) { // grid 1024 x 256
  int gid = blockIdx.x * 256 + threadIdx.x;
  int j = gid & 7, lane = (gid >> 3) & 63, ks = (gid >> 9) & 15, mt = gid >> 13;
  int m = mt * 16 + (lane & 15);              // phi: 0..510 valid
  int k = ks * 32 + ((lane >> 4) << 3) + j;   // 0..254 cos*Gre, 255..509 -sin*Gim
  float v = 0.f;
  if (m < 511 && k < 510) {
    int jj = (k < 255) ? k : k - 255;
    int jm = jj - 127;
    int kk = ((jm * m) % 511 + 511) % 511;
    double ang = (2.0 * PI_D / 511.0) * (double)kk;
    v = (k < 255) ? (float)cos(ang) : -(float)sin(ang);
  }
  ((short*)(ws + OFF_AI))[gid] = f2bf(v);
}

// ---------------- fwd-DFT B-fragment repack (wq folded) ----------------
__global__ void k_bfrag_f(const float* x, float* ws) { // grid 2048 x 256
  int gid = blockIdx.x * 256 + threadIdx.x;   // < 524288
  int lane = gid & 63, nt = (gid >> 6) & 1, ks = (gid >> 7) & 15, t = gid >> 11;
  int c = nt * 16 + (lane & 15);
  int phiB = ks * 32 + ((lane >> 4) << 3);
  float wq = ws[OFF_WQ + t];
  v8s tmp;
#pragma unroll
  for (int j = 0; j < 8; ++j) {
    int phi = phiB + j;
    tmp[j] = (phi < 511) ? f2bf(wq * x[((size_t)t * 511 + phi) * 32 + c]) : (short)0;
  }
  ((v8s*)(ws + OFF_BF))[gid] = tmp;
}

// ---------------- fwd DFT MFMA GEMM -> legfwd B-frags (bf16) ----------------
__global__ __launch_bounds__(256) void k_gemm_f(float* ws) { // grid (2, 256)
  int nt = blockIdx.x, t = blockIdx.y;
  int tid = threadIdx.x, wave = tid >> 6, lane = tid & 63;
  const v8s* A = (const v8s*)(ws + OFF_AF);
  const v8s* B = (const v8s*)(ws + OFF_BF);
  int mtB = wave * 8;
  v4f acc[8];
#pragma unroll
  for (int i = 0; i < 8; ++i) acc[i] = (v4f){0.f, 0.f, 0.f, 0.f};
  for (int ks = 0; ks < 16; ++ks) {
    v8s b = B[(size_t)((t * 16 + ks) * 2 + nt) * 64 + lane];
#pragma unroll
    for (int i = 0; i < 8; ++i) {
      v8s a = A[(size_t)((mtB + i) * 16 + ks) * 64 + lane];
      acc[i] = __builtin_amdgcn_mfma_f32_16x16x32_bf16(a, b, acc[i], 0, 0, 0);
    }
  }
  short* BF2p = (short*)(ws + OFF_BF2);
  int quad = lane >> 4, cn = nt * 16 + (lane & 15);
  int tfrag = ((((t >> 3) & 3) << 4));
#pragma unroll
  for (int i = 0; i < 8; ++i) {
    int mt = mtB + i;
#pragma unroll
    for (int r = 0; r < 4; ++r) {
      int mp = mt * 16 + quad * 4 + r;
      int m = mp & 255;
      int cp = cn + ((mp >> 8) << 5);          // re: c'=cn, im: cn+32
      size_t idx = (size_t)m * 16384 + (size_t)(t >> 5) * 2048 + (size_t)(cp >> 4) * 512 +
                   (size_t)(tfrag + (cp & 15)) * 8 + (t & 7);
      BF2p[idx] = f2bf(acc[i][r]);
    }
  }
}

// ---------------- forward Legendre MFMA: flm[m][l][c] fp32 ----------------
__global__ __launch_bounds__(256) void k_legfwd(float* ws) { // grid (2, 256)
  int half = blockIdx.x, m = blockIdx.y;
  int tid = threadIdx.x, wave = tid >> 6, lane = tid & 63;
  const v8s* A = (const v8s*)(ws + OFF_PA) + (size_t)m * 8192;
  const v8s* B = (const v8s*)(ws + OFF_BF2) + (size_t)m * 2048;
  int mt0 = half * 8 + wave * 2;
  v4f acc[2][4];
#pragma unroll
  for (int i = 0; i < 2; ++i)
#pragma unroll
    for (int n = 0; n < 4; ++n) acc[i][n] = (v4f){0.f, 0.f, 0.f, 0.f};
  bool sk0 = (mt0 * 16 + 15) < m;
  bool sk1 = (mt0 * 16 + 31) < m;
  if (!(sk0 && sk1)) {
    for (int ks = 0; ks < 8; ++ks) {
      v8s b0 = B[ks * 256 + lane];
      v8s b1 = B[ks * 256 + 64 + lane];
      v8s b2 = B[ks * 256 + 128 + lane];
      v8s b3 = B[ks * 256 + 192 + lane];
      if (!sk0) {
        v8s a = A[(size_t)mt0 * 512 + ks * 64 + lane];
        acc[0][0] = __builtin_amdgcn_mfma_f32_16x16x32_bf16(a, b0, acc[0][0], 0, 0, 0);
        acc[0][1] = __builtin_amdgcn_mfma_f32_16x16x32_bf16(a, b1, acc[0][1], 0, 0, 0);
        acc[0][2] = __builtin_amdgcn_mfma_f32_16x16x32_bf16(a, b2, acc[0][2], 0, 0, 0);
        acc[0][3] = __builtin_amdgcn_mfma_f32_16x16x32_bf16(a, b3, acc[0][3], 0, 0, 0);
      }
      if (!sk1) {
        v8s a = A[(size_t)(mt0 + 1) * 512 + ks * 64 + lane];
        acc[1][0] = __builtin_amdgcn_mfma_f32_16x16x32_bf16(a, b0, acc[1][0], 0, 0, 0);
        acc[1][1] = __builtin_amdgcn_mfma_f32_16x16x32_bf16(a, b1, acc[1][1], 0, 0, 0);
        acc[1][2] = __builtin_amdgcn_mfma_f32_16x16x32_bf16(a, b2, acc[1][2], 0, 0, 0);
        acc[1][3] = __builtin_amdgcn_mfma_f32_16x16x32_bf16(a, b3, acc[1][3], 0, 0, 0);
      }
    }
  }
  int quad = lane >> 4, cl = lane & 15;
#pragma unroll
  for (int i = 0; i < 2; ++i) {
    bool sk = i ? sk1 : sk0;
#pragma unroll
    for (int n = 0; n < 4; ++n) {
      int cp = n * 16 + cl;
      float* dst = ws + ((cp >= 32) ? OFF_SFIM : OFF_SFRE) + (size_t)m * 8192 + (cp & 31);
#pragma unroll
      for (int r = 0; r < 4; ++r) {
        int l = (mt0 + i) * 16 + quad * 4 + r;
        dst[(size_t)l * 32] = sk ? 0.f : acc[i][n][r];
      }
    }
  }
}

// ---------------- bilinear (antialias) resize, fused 2-D taps ----------------
__global__ __launch_bounds__(256) void k_resize(float* ws) { // grid 4080 x 256
  int tid = threadIdx.x;
  int p = blockIdx.x * 8 + (tid >> 5);
  int c = tid & 31;
  int lp = p & 127, jp = p >> 7;
  const float* WLW = ws + OFF_WLW;
  const int* WLI = (const int*)(ws + OFF_WLI);
  const float* WMW = ws + OFF_WMW;
  const int* WMI = (const int*)(ws + OFF_WMI);
  const float* SFRE = ws + OFF_SFRE;
  const float* SFIM = ws + OFF_SFIM;
  float accr = 0.f, acci = 0.f;
  for (int b = 0; b < 6; ++b) {
    float wm = WMW[jp * 6 + b];
    int jm = WMI[jp * 6 + b];
    bool mneg = (jm < 255);
    int mm = mneg ? (255 - jm) : (jm - 255);
    float fre_f = (mneg && (mm & 1)) ? -1.f : 1.f;
    float fim_f = mneg ? -fre_f : 1.f;
#pragma unroll
    for (int a = 0; a < 4; ++a) {
      float w = wm * WLW[lp * 4 + a];
      int li = WLI[lp * 4 + a];
      size_t base = ((size_t)mm * 256 + li) * 32 + c;
      accr = fmaf(w * fre_f, SFRE[base], accr);
      acci = fmaf(w * fim_f, SFIM[base], acci);
    }
  }
  ws[OFF_RRE + ((size_t)jp * 128 + lp) * 32 + c] = accr;
  ws[OFF_RIM + ((size_t)jp * 128 + lp) * 32 + c] = acci;
}

// ---------------- per-l complex channel mix -> leginv B-frags (bf16) ----------------
__global__ __launch_bounds__(256) void k_conv(float* ws) { // grid (32 jg, 128 l) x 256
  int jg = blockIdx.x, l = blockIdx.y;
  int tid = threadIdx.x;
  int jl = tid >> 5, o = tid & 31;
  int j = jg * 8 + jl;
  int jc = (j < 255) ? j : 254;
  __shared__ __align__(16) float wr[32 * 36];
  __shared__ __align__(16) float wi[32 * 36];
  __shared__ __align__(16) float fr[8 * 32];
  __shared__ __align__(16) float fi[8 * 32];
  {
    int oo = tid >> 3, i4 = (tid & 7) * 4;
    *(float4*)(wr + oo * 36 + i4) = ld4(ws + OFF_WPR + ((size_t)l * 32 + oo) * 32 + i4);
    *(float4*)(wi + oo * 36 + i4) = ld4(ws + OFF_WPI + ((size_t)l * 32 + oo) * 32 + i4);
  }
  size_t fbase = ((size_t)jc * 128 + l) * 32;
  fr[jl * 32 + o] = ws[OFF_RRE + fbase + o];
  fi[jl * 32 + o] = ws[OFF_RIM + fbase + o];
  __syncthreads();
  float accr = 0.f, acci = 0.f;
#pragma unroll
  for (int i0 = 0; i0 < 32; i0 += 4) {
    float4 f_r = *(const float4*)(fr + jl * 32 + i0);
    float4 f_i = *(const float4*)(fi + jl * 32 + i0);
    float4 w_r = *(const float4*)(wr + o * 36 + i0);
    float4 w_i = *(const float4*)(wi + o * 36 + i0);
    accr += f_r.x * w_r.x - f_i.x * w_i.x;  acci += f_r.x * w_i.x + f_i.x * w_r.x;
    accr += f_r.y * w_r.y - f_i.y * w_i.y;  acci += f_r.y * w_i.y + f_i.y * w_r.y;
    accr += f_r.z * w_r.z - f_i.z * w_i.z;  acci += f_r.z * w_i.z + f_i.z * w_r.z;
    accr += f_r.w * w_r.w - f_i.w * w_i.w;  acci += f_r.w * w_i.w + f_i.w * w_r.w;
  }
  if (j < 255) {
    float s = (j < 127 && ((127 - j) & 1)) ? -1.f : 1.f;   // (-1)^|m| for negative m
    short* BI2p = (short*)(ws + OFF_BI2);
    int lanehi = ((l >> 3) & 3) << 4;
    size_t base = (size_t)j * 16384 + (size_t)(l >> 5) * 2048 + (size_t)(lanehi + (o & 15)) * 8 + (l & 7);
    BI2p[base + (size_t)(o >> 4) * 512] = f2bf(s * accr);
    BI2p[base + (size_t)((o >> 4) + 2) * 512] = f2bf(s * acci);
  }
}

// ---------------- inverse Legendre MFMA -> inv-DFT B-frags (bf16) ----------------
__global__ __launch_bounds__(256) void k_gemm_linv(float* ws) { // grid (2, 255)
  int half = blockIdx.x, j = blockIdx.y;
  int d = j - 127; int mm = (d < 0) ? -d : d;
  int tid = threadIdx.x, wave = tid >> 6, lane = tid & 63;
  const v8s* A = (const v8s*)(ws + OFF_PT) + (size_t)mm * 8192;
  const v8s* B = (const v8s*)(ws + OFF_BI2) + (size_t)j * 2048;
  int mt0 = half * 8 + wave * 2;
  v4f acc[2][4];
#pragma unroll
  for (int i = 0; i < 2; ++i)
#pragma unroll
    for (int n = 0; n < 4; ++n) acc[i][n] = (v4f){0.f, 0.f, 0.f, 0.f};
  int ks0 = mm >> 5;
  // BUGFIX (R4->R5): contraction must stop at l<128 (ks<4). Padded flm is zero
  // for l>=128, and BI2's ks 4..7 region holds STALE k_bfrag_f data (overlay),
  // not zeros — reading it injected ~4e-2 garbage via nonzero PT[t][l>=128].
  for (int ks = ks0; ks < 4; ++ks) {
    v8s b0 = B[ks * 256 + lane];
    v8s b1 = B[ks * 256 + 64 + lane];
    v8s b2 = B[ks * 256 + 128 + lane];
    v8s b3 = B[ks * 256 + 192 + lane];
    v8s a0 = A[(size_t)mt0 * 512 + ks * 64 + lane];
    v8s a1 = A[(size_t)(mt0 + 1) * 512 + ks * 64 + lane];
    acc[0][0] = __builtin_amdgcn_mfma_f32_16x16x32_bf16(a0, b0, acc[0][0], 0, 0, 0);
    acc[0][1] = __builtin_amdgcn_mfma_f32_16x16x32_bf16(a0, b1, acc[0][1], 0, 0, 0);
    acc[0][2] = __builtin_amdgcn_mfma_f32_16x16x32_bf16(a0, b2, acc[0][2], 0, 0, 0);
    acc[0][3] = __builtin_amdgcn_mfma_f32_16x16x32_bf16(a0, b3, acc[0][3], 0, 0, 0);
    acc[1][0] = __builtin_amdgcn_mfma_f32_16x16x32_bf16(a1, b0, acc[1][0], 0, 0, 0);
    acc[1][1] = __builtin_amdgcn_mfma_f32_16x16x32_bf16(a1, b1, acc[1][1], 0, 0, 0);
    acc[1][2] = __builtin_amdgcn_mfma_f32_16x16x32_bf16(a1, b2, acc[1][2], 0, 0, 0);
    acc[1][3] = __builtin_amdgcn_mfma_f32_16x16x32_bf16(a1, b3, acc[1][3], 0, 0, 0);
  }
  short* BIp = (short*)(ws + OFF_BI);
  int quad = lane >> 4, cl = lane & 15;
#pragma unroll
  for (int i = 0; i < 2; ++i) {
#pragma unroll
    for (int n = 0; n < 4; ++n) {
      int cp = n * 16 + cl;
      int c = cp & 31;
      int k = j + ((cp >= 32) ? 255 : 0);
      size_t kpart = (size_t)(k >> 5) * 1024 + (size_t)(c >> 4) * 512 +
                     (size_t)((((k >> 3) & 3) << 4) + (c & 15)) * 8 + (k & 7);
#pragma unroll
      for (int r = 0; r < 4; ++r) {
        int t = (mt0 + i) * 16 + quad * 4 + r;
        BIp[(size_t)t * 16384 + kpart] = f2bf(acc[i][n][r]);
      }
    }
  }
}

// ---------------- inverse DFT MFMA GEMM -> out ----------------
__global__ __launch_bounds__(256) void k_gemm_i(const float* ws, float* out) { // grid (2, 256)
  int nt = blockIdx.x, t = blockIdx.y;
  int tid = threadIdx.x, wave = tid >> 6, lane = tid & 63;
  const v8s* A = (const v8s*)(ws + OFF_AI);
  const v8s* B = (const v8s*)(ws + OFF_BI);
  int mtB = wave * 8;
  v4f acc[8];
#pragma unroll
  for (int i = 0; i < 8; ++i) acc[i] = (v4f){0.f, 0.f, 0.f, 0.f};
  for (int ks = 0; ks < 16; ++ks) {
    v8s b = B[(size_t)((t * 16 + ks) * 2 + nt) * 64 + lane];
#pragma unroll
    for (int i = 0; i < 8; ++i) {
      v8s a = A[(size_t)((mtB + i) * 16 + ks) * 64 + lane];
      acc[i] = __builtin_amdgcn_mfma_f32_16x16x32_bf16(a, b, acc[i], 0, 0, 0);
    }
  }
  int quad = lane >> 4, cn = nt * 16 + (lane & 15);
#pragma unroll
  for (int i = 0; i < 8; ++i) {
    int mt = mtB + i;
#pragma unroll
    for (int r = 0; r < 4; ++r) {
      int phi = mt * 16 + quad * 4 + r;
      if (phi < 511) out[((size_t)t * 511 + phi) * 32 + cn] = acc[i][r];
    }
  }
}

// ---------------- launch ----------------
extern "C" void kernel_launch(void* const* d_in, const int* in_sizes, int n_in,
                              void* d_out, int out_size, void* d_ws, size_t ws_size,
                              hipStream_t stream) {
  const float* x = (const float*)d_in[0];
  const float* t_emb = (const float*)d_in[1];
  const float* w_real = (const float*)d_in[2];
  const float* w_imag = (const float*)d_in[3];
  const float* w_tr = (const float*)d_in[4];
  const float* b_tr = (const float*)d_in[5];
  const float* w_ti = (const float*)d_in[6];
  const float* b_ti = (const float*)d_in[7];
  float* ws = (float*)d_ws;
  float* out = (float*)d_out;
  (void)in_sizes; (void)n_in; (void)out_size; (void)ws_size;

  hipLaunchKernelGGL(k_setup_small, dim3(1), dim3(256), 0, stream,
                     t_emb, w_tr, b_tr, w_ti, b_ti, ws);
  hipLaunchKernelGGL(k_wprep, dim3(512), dim3(256), 0, stream, w_real, w_imag, ws);
  hipLaunchKernelGGL(k_legendre, dim3(256), dim3(256), 0, stream, ws);
  hipLaunchKernelGGL(k_atab_f, dim3(1024), dim3(256), 0, stream, ws);
  hipLaunchKernelGGL(k_atab_i, dim3(1024), dim3(256), 0, stream, ws);
  hipLaunchKernelGGL(k_bfrag_f, dim3(2048), dim3(256), 0, stream, x, ws);
  hipLaunchKernelGGL(k_gemm_f, dim3(2, 256), dim3(256), 0, stream, ws);
  hipLaunchKernelGGL(k_legfwd, dim3(2, 256), dim3(256), 0, stream, ws);
  hipLaunchKernelGGL(k_resize, dim3(4080), dim3(256), 0, stream, ws);
  hipLaunchKernelGGL(k_conv, dim3(32, 128), dim3(256), 0, stream, ws);
  hipLaunchKernelGGL(k_gemm_linv, dim3(2, 255), dim3(256), 0, stream, ws);
  hipLaunchKernelGGL(k_gemm_i, dim3(2, 256), dim3(256), 0, stream, ws, out);
}

// Round 6
// 254.481 us; speedup vs baseline: 1.0279x; 1.0279x over previous
//
#include <hip/hip_runtime.h>
#include <math.h>

#define PI_D 3.14159265358979323846

typedef short v8s __attribute__((ext_vector_type(8)));
typedef float v4f __attribute__((ext_vector_type(4)));

// ---------------- workspace layout (float offsets), total 23.6M floats = 94.4 MB ----------------
constexpr size_t OFF_PA   = 0;                   // legfwd A-frags bf16: per m, A[l][t]  (256 slices, 32 MB)
constexpr size_t OFF_PT   = 8388608;             // leginv A-frags bf16: per m, A[t][l]  (128 slices, 16 MB)
constexpr size_t OFF_SFRE = 12582912;            // flm re [m][l][c] fp32 (8 MB)
constexpr size_t OFF_SFIM = 14680064;            // flm im
constexpr size_t OFF_BF   = 16777216;            // fwd-DFT B-frags bf16 [t][ks16][nt2][lane][8] (8 MB)
constexpr size_t OFF_BF2  = 18874368;            // legfwd B-frags bf16 [m][ks8][nt4][lane][8] (8 MB)
constexpr size_t OFF_BI   = 20971520;            // inv-DFT B-frags bf16 [t][ks16][nt2][lane][8] (8 MB)
constexpr size_t OFF_AF   = 23068672;            // fwd DFT A-frags bf16 (512 KB)
constexpr size_t OFF_AI   = 23199744;            // inv DFT A-frags bf16 (512 KB)
constexpr size_t OFF_WPR  = 23330816;            // premult conv w [l][o][i] fp32
constexpr size_t OFF_WPI  = 23461888;
constexpr size_t OFF_WQ   = 23592960;            // 256 quadrature weights
constexpr size_t OFF_TC   = 23593216;            // 256 (t_cplx re|im)
constexpr size_t OFF_WLW  = 23593472;            // 128*4 l-resize weights
constexpr size_t OFF_WLI  = 23593984;            // 128*4 l-resize indices (int)
constexpr size_t OFF_WMW  = 23594496;            // 255*6 m-resize weights
constexpr size_t OFF_WMI  = 23596032;            // 255*6 m-resize indices (int)
// overlays (lifetimes disjoint):
constexpr size_t OFF_BI2  = OFF_BF;              // leginv B-frags bf16 [j][ks4][nt4][lane][8]; ONLY ks 0..3
                                                 // valid (l<128) — ks 4..7 hold stale BF data, never read!
constexpr size_t OFF_RRE  = OFF_BF2;             // resized flm [j'][l'][c] fp32 (BF2 dead after legfwd)
constexpr size_t OFF_RIM  = OFF_BF2 + 1044480;

__device__ __forceinline__ float4 ld4(const float* p) { return *(const float4*)p; }

__device__ __forceinline__ short f2bf(float f) {   // RTNE float->bf16 bits
  unsigned u = __float_as_uint(f);
  unsigned r = (u + 0x7FFFu + ((u >> 16) & 1u)) >> 16;
  return (short)r;
}

// ---------------- setup: quadrature, t_cplx, resize taps ----------------
__global__ void k_setup_small(const float* t_emb, const float* w_tr, const float* b_tr,
                              const float* w_ti, const float* b_ti, float* ws) {
  int tid = threadIdx.x;
  if (tid < 256) {
    double theta = PI_D * (2.0 * tid + 1.0) / 511.0;
    double dang = 2.0 * PI_D / 511.0;
    ws[OFF_WQ + tid] = (float)(sin(theta) * dang * dang);
  }
  {
    // t_cplx: 256 threads, half re / half im
    int h = tid >> 7, o = tid & 127;
    const float* W = h ? w_ti : w_tr;
    float s = h ? b_ti[o] : b_tr[o];
    for (int T = 0; T < 256; ++T) s += t_emb[T] * W[T * 128 + o];
    ws[OFF_TC + h * 128 + o] = s;
  }
  if (tid < 128) {
    double sf = 2.0 * tid + 0.5;
    double wv[4]; int iv[4]; double wsum = 0.0;
    for (int a = 0; a < 4; ++a) {
      int t = 2 * tid - 1 + a;
      double r = 1.0 - fabs(sf - (double)t) * 0.5;
      bool valid = (t >= 0 && t < 256 && r > 0.0);
      wv[a] = valid ? r : 0.0; iv[a] = valid ? t : 0;
      wsum += wv[a];
    }
    for (int a = 0; a < 4; ++a) {
      ws[OFF_WLW + tid * 4 + a] = (float)(wv[a] / wsum);
      ((int*)(ws + OFF_WLI))[tid * 4 + a] = iv[a];
    }
  }
  if (tid < 255) {
    double inv = 511.0 / 255.0;
    double sf = (tid + 0.5) * inv - 0.5;
    int t0 = (int)floor(sf) - 2;
    double wv[6]; int iv[6]; double wsum = 0.0;
    for (int b = 0; b < 6; ++b) {
      int t = t0 + b;
      double r = 1.0 - fabs(sf - (double)t) * (255.0 / 511.0);
      bool valid = (t >= 0 && t < 511 && r > 0.0);
      wv[b] = valid ? r : 0.0; iv[b] = valid ? t : 0;
      wsum += wv[b];
    }
    for (int b = 0; b < 6; ++b) {
      ws[OFF_WMW + tid * 6 + b] = (float)(wv[b] / wsum);
      ((int*)(ws + OFF_WMI))[tid * 6 + b] = iv[b];
    }
  }
}

// ---------------- premultiplied conv weights, transposed [l][o][i] ----------------
__global__ void k_wprep(const float* wr_, const float* wi_, float* ws) { // grid 512 x 256
  int gid = blockIdx.x * 256 + threadIdx.x;
  int l = gid >> 10, rem = gid & 1023, o = rem >> 5, i = rem & 31;
  float wr = wr_[(l << 10) + i * 32 + o];
  float wi = wi_[(l << 10) + i * 32 + o];
  float tcr = ws[OFF_TC + l], tci = ws[OFF_TC + 128 + l];
  ws[OFF_WPR + gid] = tcr * wr - tci * wi;
  ws[OFF_WPI + gid] = tcr * wi + tci * wr;
}

// ---------------- Legendre basis -> bf16 MFMA A-frag tables (LDS-staged, coalesced) ----------------
// PA[m]: A[row=l][col=t]; PT[m<128]: A[row=t][col=l]. Frag elem (row,col):
//   idx = (row>>4)*4096 + (col>>5)*512 + (((col>>3)&3)*16 + (row&15))*8 + (col&7)
// R5->R6: old version did 2-byte scattered stores (16B apart) -> ~1 TB/s effective, 48 us.
// Now stage 16-l chunks in LDS, emit 16B coalesced chunk stores (chunk = 8 consecutive shorts).
__global__ __launch_bounds__(256) void k_legendre(float* ws) {   // grid 256 (m) x 256 (t)
  int m = blockIdx.x, t = threadIdx.x;
  __shared__ double cA[256], cB[256], cS[256];
  {
    int l = t;
    if (l >= 1) cS[l] = -sqrt((2.0 * l + 1.0) / (2.0 * l));
    if (l >= m + 2) {
      double ll = l, mm = m;
      double den = ll * ll - mm * mm;
      cA[l] = sqrt((4.0 * ll * ll - 1.0) / den);
      cB[l] = sqrt((2.0 * ll + 1.0) * (ll - 1.0 - mm) * (ll - 1.0 + mm) /
                   ((2.0 * ll - 3.0) * den));
    }
  }
  __syncthreads();
  __shared__ short tile[16 * 280];    // [l&15][t], row stride 280 shorts (560B = 16*35, 16B-aligned rows)
  __shared__ short tileT[256 * 34];   // [t][l&15], row stride 34 shorts (68B, 4B-aligned)
  bool wantPT = (m < 128);
  short* PAp = (short*)(ws + OFF_PA) + (size_t)m * 65536;
  short* PTp = (short*)(ws + OFF_PT) + (size_t)m * 65536;
  double theta = PI_D * (2.0 * t + 1.0) / 511.0;
  double ct = cos(theta), st = sin(theta);
  double p0 = sqrt(1.0 / (4.0 * PI_D));
  for (int k = 1; k <= m; ++k) p0 *= cS[k] * st;
  double pm1 = 0.0, pcur = 0.0;
  for (int lt = 0; lt < 16; ++lt) {
    for (int li = 0; li < 16; ++li) {
      int l = lt * 16 + li;
      float v;
      if (l < m) v = 0.f;
      else if (l == m) { pcur = p0; v = (float)pcur; }
      else if (l == m + 1) { pm1 = pcur; pcur = sqrt(2.0 * m + 3.0) * ct * pm1; v = (float)pcur; }
      else { double p2 = cA[l] * ct * pcur - cB[l] * pm1; pm1 = pcur; pcur = p2; v = (float)p2; }
      short bv = f2bf(v);
      tile[li * 280 + t] = bv;
      if (wantPT) tileT[t * 34 + li] = bv;
    }
    __syncthreads();
    // PA: 512 chunks; chunk ch: li = ch&15, T0 = ch>>4 -> t = T0*8..T0*8+7 (consecutive shorts)
#pragma unroll
    for (int pass = 0; pass < 2; ++pass) {
      int ch = pass * 256 + t;
      int li = ch & 15, T0 = ch >> 4;
      size_t dst = (size_t)lt * 4096 + (size_t)(T0 >> 2) * 512 + (size_t)((T0 & 3) * 16 + li) * 8;
      *(v8s*)(PAp + dst) = *(const v8s*)(tile + li * 280 + T0 * 8);
    }
    if (wantPT) {
      // PT: 512 chunks; chunk ch: tt = ch>>1, li0 = (ch&1)*8 -> l = lt*16+li0..+7 (consecutive shorts)
#pragma unroll
      for (int pass = 0; pass < 2; ++pass) {
        int ch = pass * 256 + t;
        int tt = ch >> 1, li0 = (ch & 1) * 8;
        size_t dst = (size_t)(tt >> 4) * 4096 + (size_t)(lt >> 1) * 512 +
                     (size_t)(((lt & 1) * 2 + (li0 >> 3)) * 16 + (tt & 15)) * 8;
        const int* src = (const int*)(tileT + tt * 34 + li0);
        int* d = (int*)(PTp + dst);
        d[0] = src[0]; d[1] = src[1]; d[2] = src[2]; d[3] = src[3];
      }
    }
    __syncthreads();
  }
}

// ---------------- DFT A-fragment tables (bf16, MFMA A-operand layout), fused ----------------
__global__ void k_atab(float* ws) { // grid 2048 x 256
  int g = blockIdx.x * 256 + threadIdx.x;
  if (g < 262144) {
    int gid = g;
    int j = gid & 7, lane = (gid >> 3) & 63, ks = (gid >> 9) & 15, mt = gid >> 13;
    int m = mt * 16 + (lane & 15);              // m' : 0..255 cos rows, 256..511 -sin rows
    int k = ks * 32 + ((lane >> 4) << 3) + j;   // phi
    float v = 0.f;
    if (k < 511) {
      int mm = (m < 256) ? m : m - 256;
      int kk = (mm * k) % 511;
      double ang = (2.0 * PI_D / 511.0) * (double)kk;
      v = (m < 256) ? (float)cos(ang) : -(float)sin(ang);
    }
    ((short*)(ws + OFF_AF))[gid] = f2bf(v);
  } else {
    int gid = g - 262144;
    int j = gid & 7, lane = (gid >> 3) & 63, ks = (gid >> 9) & 15, mt = gid >> 13;
    int m = mt * 16 + (lane & 15);              // phi: 0..510 valid
    int k = ks * 32 + ((lane >> 4) << 3) + j;   // 0..254 cos*Gre, 255..509 -sin*Gim
    float v = 0.f;
    if (m < 511 && k < 510) {
      int jj = (k < 255) ? k : k - 255;
      int jm = jj - 127;
      int kk = ((jm * m) % 511 + 511) % 511;
      double ang = (2.0 * PI_D / 511.0) * (double)kk;
      v = (k < 255) ? (float)cos(ang) : -(float)sin(ang);
    }
    ((short*)(ws + OFF_AI))[gid] = f2bf(v);
  }
}

// ---------------- fwd-DFT B-fragment repack (wq folded) ----------------
__global__ void k_bfrag_f(const float* x, float* ws) { // grid 2048 x 256
  int gid = blockIdx.x * 256 + threadIdx.x;   // < 524288
  int lane = gid & 63, nt = (gid >> 6) & 1, ks = (gid >> 7) & 15, t = gid >> 11;
  int c = nt * 16 + (lane & 15);
  int phiB = ks * 32 + ((lane >> 4) << 3);
  float wq = ws[OFF_WQ + t];
  v8s tmp;
#pragma unroll
  for (int j = 0; j < 8; ++j) {
    int phi = phiB + j;
    tmp[j] = (phi < 511) ? f2bf(wq * x[((size_t)t * 511 + phi) * 32 + c]) : (short)0;
  }
  ((v8s*)(ws + OFF_BF))[gid] = tmp;
}

// ---------------- fwd DFT MFMA GEMM -> legfwd B-frags (bf16) ----------------
__global__ __launch_bounds__(256) void k_gemm_f(float* ws) { // grid (2, 256)
  int nt = blockIdx.x, t = blockIdx.y;
  int tid = threadIdx.x, wave = tid >> 6, lane = tid & 63;
  const v8s* A = (const v8s*)(ws + OFF_AF);
  const v8s* B = (const v8s*)(ws + OFF_BF);
  int mtB = wave * 8;
  v4f acc[8];
#pragma unroll
  for (int i = 0; i < 8; ++i) acc[i] = (v4f){0.f, 0.f, 0.f, 0.f};
  for (int ks = 0; ks < 16; ++ks) {
    v8s b = B[(size_t)((t * 16 + ks) * 2 + nt) * 64 + lane];
#pragma unroll
    for (int i = 0; i < 8; ++i) {
      v8s a = A[(size_t)((mtB + i) * 16 + ks) * 64 + lane];
      acc[i] = __builtin_amdgcn_mfma_f32_16x16x32_bf16(a, b, acc[i], 0, 0, 0);
    }
  }
  short* BF2p = (short*)(ws + OFF_BF2);
  int quad = lane >> 4, cn = nt * 16 + (lane & 15);
  int tfrag = ((((t >> 3) & 3) << 4));
#pragma unroll
  for (int i = 0; i < 8; ++i) {
    int mt = mtB + i;
#pragma unroll
    for (int r = 0; r < 4; ++r) {
      int mp = mt * 16 + quad * 4 + r;
      int m = mp & 255;
      int cp = cn + ((mp >> 8) << 5);          // re: c'=cn, im: cn+32
      size_t idx = (size_t)m * 16384 + (size_t)(t >> 5) * 2048 + (size_t)(cp >> 4) * 512 +
                   (size_t)(tfrag + (cp & 15)) * 8 + (t & 7);
      BF2p[idx] = f2bf(acc[i][r]);
    }
  }
}

// ---------------- forward Legendre MFMA: flm[m][l][c] fp32 ----------------
__global__ __launch_bounds__(256) void k_legfwd(float* ws) { // grid (2, 256)
  int half = blockIdx.x, m = blockIdx.y;
  int tid = threadIdx.x, wave = tid >> 6, lane = tid & 63;
  const v8s* A = (const v8s*)(ws + OFF_PA) + (size_t)m * 8192;
  const v8s* B = (const v8s*)(ws + OFF_BF2) + (size_t)m * 2048;
  int mt0 = half * 8 + wave * 2;
  v4f acc[2][4];
#pragma unroll
  for (int i = 0; i < 2; ++i)
#pragma unroll
    for (int n = 0; n < 4; ++n) acc[i][n] = (v4f){0.f, 0.f, 0.f, 0.f};
  bool sk0 = (mt0 * 16 + 15) < m;
  bool sk1 = (mt0 * 16 + 31) < m;
  if (!(sk0 && sk1)) {
    for (int ks = 0; ks < 8; ++ks) {
      v8s b0 = B[ks * 256 + lane];
      v8s b1 = B[ks * 256 + 64 + lane];
      v8s b2 = B[ks * 256 + 128 + lane];
      v8s b3 = B[ks * 256 + 192 + lane];
      if (!sk0) {
        v8s a = A[(size_t)mt0 * 512 + ks * 64 + lane];
        acc[0][0] = __builtin_amdgcn_mfma_f32_16x16x32_bf16(a, b0, acc[0][0], 0, 0, 0);
        acc[0][1] = __builtin_amdgcn_mfma_f32_16x16x32_bf16(a, b1, acc[0][1], 0, 0, 0);
        acc[0][2] = __builtin_amdgcn_mfma_f32_16x16x32_bf16(a, b2, acc[0][2], 0, 0, 0);
        acc[0][3] = __builtin_amdgcn_mfma_f32_16x16x32_bf16(a, b3, acc[0][3], 0, 0, 0);
      }
      if (!sk1) {
        v8s a = A[(size_t)(mt0 + 1) * 512 + ks * 64 + lane];
        acc[1][0] = __builtin_amdgcn_mfma_f32_16x16x32_bf16(a, b0, acc[1][0], 0, 0, 0);
        acc[1][1] = __builtin_amdgcn_mfma_f32_16x16x32_bf16(a, b1, acc[1][1], 0, 0, 0);
        acc[1][2] = __builtin_amdgcn_mfma_f32_16x16x32_bf16(a, b2, acc[1][2], 0, 0, 0);
        acc[1][3] = __builtin_amdgcn_mfma_f32_16x16x32_bf16(a, b3, acc[1][3], 0, 0, 0);
      }
    }
  }
  int quad = lane >> 4, cl = lane & 15;
#pragma unroll
  for (int i = 0; i < 2; ++i) {
    bool sk = i ? sk1 : sk0;
#pragma unroll
    for (int n = 0; n < 4; ++n) {
      int cp = n * 16 + cl;
      float* dst = ws + ((cp >= 32) ? OFF_SFIM : OFF_SFRE) + (size_t)m * 8192 + (cp & 31);
#pragma unroll
      for (int r = 0; r < 4; ++r) {
        int l = (mt0 + i) * 16 + quad * 4 + r;
        dst[(size_t)l * 32] = sk ? 0.f : acc[i][n][r];
      }
    }
  }
}

// ---------------- bilinear (antialias) resize, fused 2-D taps ----------------
__global__ __launch_bounds__(256) void k_resize(float* ws) { // grid 4080 x 256
  int tid = threadIdx.x;
  int p = blockIdx.x * 8 + (tid >> 5);
  int c = tid & 31;
  int lp = p & 127, jp = p >> 7;
  const float* WLW = ws + OFF_WLW;
  const int* WLI = (const int*)(ws + OFF_WLI);
  const float* WMW = ws + OFF_WMW;
  const int* WMI = (const int*)(ws + OFF_WMI);
  const float* SFRE = ws + OFF_SFRE;
  const float* SFIM = ws + OFF_SFIM;
  float accr = 0.f, acci = 0.f;
  for (int b = 0; b < 6; ++b) {
    float wm = WMW[jp * 6 + b];
    int jm = WMI[jp * 6 + b];
    bool mneg = (jm < 255);
    int mm = mneg ? (255 - jm) : (jm - 255);
    float fre_f = (mneg && (mm & 1)) ? -1.f : 1.f;
    float fim_f = mneg ? -fre_f : 1.f;
#pragma unroll
    for (int a = 0; a < 4; ++a) {
      float w = wm * WLW[lp * 4 + a];
      int li = WLI[lp * 4 + a];
      size_t base = ((size_t)mm * 256 + li) * 32 + c;
      accr = fmaf(w * fre_f, SFRE[base], accr);
      acci = fmaf(w * fim_f, SFIM[base], acci);
    }
  }
  ws[OFF_RRE + ((size_t)jp * 128 + lp) * 32 + c] = accr;
  ws[OFF_RIM + ((size_t)jp * 128 + lp) * 32 + c] = acci;
}

// ---------------- per-l complex channel mix -> leginv B-frags (bf16) ----------------
// R5->R6: grid (32,128)->(4,128); weights hoisted to LDS once, 8 j-groups per block.
__global__ __launch_bounds__(256) void k_conv(float* ws) { // grid (4 jq, 128 l) x 256
  int jq = blockIdx.x, l = blockIdx.y;
  int tid = threadIdx.x;
  int jl = tid >> 5, o = tid & 31;
  __shared__ __align__(16) float wr[32 * 36];
  __shared__ __align__(16) float wi[32 * 36];
  __shared__ __align__(16) float fr[8 * 32];
  __shared__ __align__(16) float fi[8 * 32];
  {
    int oo = tid >> 3, i4 = (tid & 7) * 4;
    *(float4*)(wr + oo * 36 + i4) = ld4(ws + OFF_WPR + ((size_t)l * 32 + oo) * 32 + i4);
    *(float4*)(wi + oo * 36 + i4) = ld4(ws + OFF_WPI + ((size_t)l * 32 + oo) * 32 + i4);
  }
  short* BI2p = (short*)(ws + OFF_BI2);
  for (int ji = 0; ji < 8; ++ji) {
    int j = jq * 64 + ji * 8 + jl;
    int jc = (j < 255) ? j : 254;
    __syncthreads();
    size_t fbase = ((size_t)jc * 128 + l) * 32;
    fr[jl * 32 + o] = ws[OFF_RRE + fbase + o];
    fi[jl * 32 + o] = ws[OFF_RIM + fbase + o];
    __syncthreads();
    float accr = 0.f, acci = 0.f;
#pragma unroll
    for (int i0 = 0; i0 < 32; i0 += 4) {
      float4 f_r = *(const float4*)(fr + jl * 32 + i0);
      float4 f_i = *(const float4*)(fi + jl * 32 + i0);
      float4 w_r = *(const float4*)(wr + o * 36 + i0);
      float4 w_i = *(const float4*)(wi + o * 36 + i0);
      accr += f_r.x * w_r.x - f_i.x * w_i.x;  acci += f_r.x * w_i.x + f_i.x * w_r.x;
      accr += f_r.y * w_r.y - f_i.y * w_i.y;  acci += f_r.y * w_i.y + f_i.y * w_r.y;
      accr += f_r.z * w_r.z - f_i.z * w_i.z;  acci += f_r.z * w_i.z + f_i.z * w_r.z;
      accr += f_r.w * w_r.w - f_i.w * w_i.w;  acci += f_r.w * w_i.w + f_i.w * w_r.w;
    }
    if (j < 255) {
      float s = (j < 127 && ((127 - j) & 1)) ? -1.f : 1.f;   // (-1)^|m| for negative m
      int lanehi = ((l >> 3) & 3) << 4;
      size_t base = (size_t)j * 16384 + (size_t)(l >> 5) * 2048 + (size_t)(lanehi + (o & 15)) * 8 + (l & 7);
      BI2p[base + (size_t)(o >> 4) * 512] = f2bf(s * accr);
      BI2p[base + (size_t)((o >> 4) + 2) * 512] = f2bf(s * acci);
    }
  }
}

// ---------------- inverse Legendre MFMA -> inv-DFT B-frags (bf16) ----------------
__global__ __launch_bounds__(256) void k_gemm_linv(float* ws) { // grid (2, 255)
  int half = blockIdx.x, j = blockIdx.y;
  int d = j - 127; int mm = (d < 0) ? -d : d;
  int tid = threadIdx.x, wave = tid >> 6, lane = tid & 63;
  const v8s* A = (const v8s*)(ws + OFF_PT) + (size_t)mm * 8192;
  const v8s* B = (const v8s*)(ws + OFF_BI2) + (size_t)j * 2048;
  int mt0 = half * 8 + wave * 2;
  v4f acc[2][4];
#pragma unroll
  for (int i = 0; i < 2; ++i)
#pragma unroll
    for (int n = 0; n < 4; ++n) acc[i][n] = (v4f){0.f, 0.f, 0.f, 0.f};
  int ks0 = mm >> 5;
  // contraction stops at l<128 (ks<4): padded flm is zero for l>=128, and BI2's
  // ks 4..7 region holds STALE overlay data (see R4 post-mortem).
  for (int ks = ks0; ks < 4; ++ks) {
    v8s b0 = B[ks * 256 + lane];
    v8s b1 = B[ks * 256 + 64 + lane];
    v8s b2 = B[ks * 256 + 128 + lane];
    v8s b3 = B[ks * 256 + 192 + lane];
    v8s a0 = A[(size_t)mt0 * 512 + ks * 64 + lane];
    v8s a1 = A[(size_t)(mt0 + 1) * 512 + ks * 64 + lane];
    acc[0][0] = __builtin_amdgcn_mfma_f32_16x16x32_bf16(a0, b0, acc[0][0], 0, 0, 0);
    acc[0][1] = __builtin_amdgcn_mfma_f32_16x16x32_bf16(a0, b1, acc[0][1], 0, 0, 0);
    acc[0][2] = __builtin_amdgcn_mfma_f32_16x16x32_bf16(a0, b2, acc[0][2], 0, 0, 0);
    acc[0][3] = __builtin_amdgcn_mfma_f32_16x16x32_bf16(a0, b3, acc[0][3], 0, 0, 0);
    acc[1][0] = __builtin_amdgcn_mfma_f32_16x16x32_bf16(a1, b0, acc[1][0], 0, 0, 0);
    acc[1][1] = __builtin_amdgcn_mfma_f32_16x16x32_bf16(a1, b1, acc[1][1], 0, 0, 0);
    acc[1][2] = __builtin_amdgcn_mfma_f32_16x16x32_bf16(a1, b2, acc[1][2], 0, 0, 0);
    acc[1][3] = __builtin_amdgcn_mfma_f32_16x16x32_bf16(a1, b3, acc[1][3], 0, 0, 0);
  }
  short* BIp = (short*)(ws + OFF_BI);
  int quad = lane >> 4, cl = lane & 15;
#pragma unroll
  for (int i = 0; i < 2; ++i) {
#pragma unroll
    for (int n = 0; n < 4; ++n) {
      int cp = n * 16 + cl;
      int c = cp & 31;
      int k = j + ((cp >= 32) ? 255 : 0);
      size_t kpart = (size_t)(k >> 5) * 1024 + (size_t)(c >> 4) * 512 +
                     (size_t)((((k >> 3) & 3) << 4) + (c & 15)) * 8 + (k & 7);
#pragma unroll
      for (int r = 0; r < 4; ++r) {
        int t = (mt0 + i) * 16 + quad * 4 + r;
        BIp[(size_t)t * 16384 + kpart] = f2bf(acc[i][n][r]);
      }
    }
  }
}

// ---------------- inverse DFT MFMA GEMM -> out ----------------
__global__ __launch_bounds__(256) void k_gemm_i(const float* ws, float* out) { // grid (2, 256)
  int nt = blockIdx.x, t = blockIdx.y;
  int tid = threadIdx.x, wave = tid >> 6, lane = tid & 63;
  const v8s* A = (const v8s*)(ws + OFF_AI);
  const v8s* B = (const v8s*)(ws + OFF_BI);
  int mtB = wave * 8;
  v4f acc[8];
#pragma unroll
  for (int i = 0; i < 8; ++i) acc[i] = (v4f){0.f, 0.f, 0.f, 0.f};
  for (int ks = 0; ks < 16; ++ks) {
    v8s b = B[(size_t)((t * 16 + ks) * 2 + nt) * 64 + lane];
#pragma unroll
    for (int i = 0; i < 8; ++i) {
      v8s a = A[(size_t)((mtB + i) * 16 + ks) * 64 + lane];
      acc[i] = __builtin_amdgcn_mfma_f32_16x16x32_bf16(a, b, acc[i], 0, 0, 0);
    }
  }
  int quad = lane >> 4, cn = nt * 16 + (lane & 15);
#pragma unroll
  for (int i = 0; i < 8; ++i) {
    int mt = mtB + i;
#pragma unroll
    for (int r = 0; r < 4; ++r) {
      int phi = mt * 16 + quad * 4 + r;
      if (phi < 511) out[((size_t)t * 511 + phi) * 32 + cn] = acc[i][r];
    }
  }
}

// ---------------- launch ----------------
extern "C" void kernel_launch(void* const* d_in, const int* in_sizes, int n_in,
                              void* d_out, int out_size, void* d_ws, size_t ws_size,
                              hipStream_t stream) {
  const float* x = (const float*)d_in[0];
  const float* t_emb = (const float*)d_in[1];
  const float* w_real = (const float*)d_in[2];
  const float* w_imag = (const float*)d_in[3];
  const float* w_tr = (const float*)d_in[4];
  const float* b_tr = (const float*)d_in[5];
  const float* w_ti = (const float*)d_in[6];
  const float* b_ti = (const float*)d_in[7];
  float* ws = (float*)d_ws;
  float* out = (float*)d_out;
  (void)in_sizes; (void)n_in; (void)out_size; (void)ws_size;

  hipLaunchKernelGGL(k_setup_small, dim3(1), dim3(256), 0, stream,
                     t_emb, w_tr, b_tr, w_ti, b_ti, ws);
  hipLaunchKernelGGL(k_wprep, dim3(512), dim3(256), 0, stream, w_real, w_imag, ws);
  hipLaunchKernelGGL(k_legendre, dim3(256), dim3(256), 0, stream, ws);
  hipLaunchKernelGGL(k_atab, dim3(2048), dim3(256), 0, stream, ws);
  hipLaunchKernelGGL(k_bfrag_f, dim3(2048), dim3(256), 0, stream, x, ws);
  hipLaunchKernelGGL(k_gemm_f, dim3(2, 256), dim3(256), 0, stream, ws);
  hipLaunchKernelGGL(k_legfwd, dim3(2, 256), dim3(256), 0, stream, ws);
  hipLaunchKernelGGL(k_resize, dim3(4080), dim3(256), 0, stream, ws);
  hipLaunchKernelGGL(k_conv, dim3(4, 128), dim3(256), 0, stream, ws);
  hipLaunchKernelGGL(k_gemm_linv, dim3(2, 255), dim3(256), 0, stream, ws);
  hipLaunchKernelGGL(k_gemm_i, dim3(2, 256), dim3(256), 0, stream, ws, out);
}